// Round 2
// baseline (51832.434 us; speedup 1.0000x reference)
//
#include <hip/hip_runtime.h>
#include <hip/hip_cooperative_groups.h>
#include <math.h>

namespace cg = cooperative_groups;

#define T_DIM 1024
#define B_DIM 64
#define H_DIM 512
#define EPS_F 1e-5f

// ---- ws float offsets ----
#define WS_SUM    0                      // 512
#define WS_SUMSQ  512                    // 512
#define WS_HT     1024                   // [2 par][2 dir][512 k][64 b]
#define WS_CT     (WS_HT + 131072)       // [2 dir][512 hid][64 b]
#define WS_XZ     (WS_CT + 65536)        // [2 par][2 dir][2048 col][64 b]
#define WS_YT     (WS_XZ + 524288)       // [2 par][2 dir][512 k][64 b]
#define WS_END    (WS_YT + 131072)
#define WS_ZERO_END WS_XZ                // zero SUM/SUMSQ/HT/CT

__device__ __forceinline__ float sigf(float v) {
    return 1.0f / (1.0f + __expf(-v));
}

__global__ __launch_bounds__(512)
void brnn_persistent(const float* __restrict__ x, const int* __restrict__ lengths,
                     const float* __restrict__ scale, const float* __restrict__ bias,
                     const float* __restrict__ Wx_f, const float* __restrict__ Wh_f,
                     const float* __restrict__ b_f,
                     const float* __restrict__ Wx_b, const float* __restrict__ Wh_b,
                     const float* __restrict__ b_b,
                     const int* __restrict__ training,
                     float* __restrict__ ws, float* __restrict__ out) {
    cg::grid_group grid = cg::this_grid();

    // red: [8 waves][32 cols][64+1 b] stride 65 -> conflict-free writes/reads
    __shared__ union {
        float red[8 * 2080];     // 66.6 KB
        float tile[512 * 9];     // role-2 transpose tile (8 b, pad to 9)
    } U;
    __shared__ float a_sh[512], c0_sh[512];
    __shared__ int lsh[64];

    const int tid = threadIdx.x;
    const int bid = blockIdx.x;

    // ---------- P1: BN column stats (all 256 blocks, 256 rows each) ----------
    {
        float s = 0.f, s2 = 0.f;
        const float* xp = x + (size_t)bid * 256 * 512 + tid;
#pragma unroll 8
        for (int r = 0; r < 256; ++r) {
            float v = xp[(size_t)r * 512];
            s += v; s2 += v * v;
        }
        atomicAdd(&ws[WS_SUM + tid], s);
        atomicAdd(&ws[WS_SUMSQ + tid], s2);
    }
    grid.sync();

    // ---------- P2: per-block BN coefs + lengths into LDS ----------
    if (tid < 64) lsh[tid] = lengths[tid];
    __syncthreads();
    {
        float cnt = 0.f;
        for (int b = 0; b < 64; ++b) cnt += (float)lsh[b];
        float a, c0;
        if (*training) {
            float inv = 1.0f / cnt;
            float mean = ws[WS_SUM + tid] * inv;
            float mean2 = ws[WS_SUMSQ + tid] * inv;
            float var = fmaxf(0.f, mean2 - mean * mean);
            a = scale[tid] * rsqrtf(var + EPS_F);
            c0 = bias[tid] - mean * a;
        } else {
            a = scale[tid] * rsqrtf(1.0f + EPS_F);
            c0 = bias[tid];
        }
        a_sh[tid] = a;
        c0_sh[tid] = c0;
    }
    __syncthreads();

    const int w = __builtin_amdgcn_readfirstlane(tid >> 6);  // wave id 0..7 (uniform)
    const int lane = tid & 63;
    const int kbase = w * 64;

    // ---------- main loop ----------
    for (int i = -2; i <= 1023; ++i) {
        if (bid < 128) {
            // ===== role 0: recurrence step t=i =====
            if (i >= 0) {
                const int dir = bid >> 6;
                const int hb = bid & 63;
                const int hbase = hb << 3;
                const int p = i & 1;
                const float* __restrict__ Wh = dir ? Wh_b : Wh_f;
                const float* arow = ws + WS_HT + ((size_t)(p * 2 + dir) * 512 + kbase) * 64 + lane;
                const float* wp = Wh + (size_t)kbase * 2048 + hbase;
                float acc[32];
#pragma unroll
                for (int c = 0; c < 32; ++c) acc[c] = 0.f;
#pragma unroll 4
                for (int kk = 0; kk < 64; ++kk) {
                    float av = arow[kk * 64];           // coalesced b32, 1 per 32 FMA
                    const float* wr = wp + (size_t)kk * 2048;  // uniform addr -> s_load
#pragma unroll
                    for (int g = 0; g < 4; ++g)
#pragma unroll
                        for (int j = 0; j < 8; ++j)
                            acc[g * 8 + j] = fmaf(wr[g * 512 + j], av, acc[g * 8 + j]);
                }
                __syncthreads();
#pragma unroll
                for (int c = 0; c < 32; ++c) U.red[w * 2080 + c * 65 + lane] = acc[c];
                __syncthreads();
                // gates: thread -> (b = tid&63, h8 = tid>>6)
                const int b = tid & 63;
                const int h8 = tid >> 6;
                const int hid = hbase + h8;
                const float* xzp = ws + WS_XZ + (size_t)(p * 2 + dir) * 2048 * 64;
                float z[4];
#pragma unroll
                for (int g = 0; g < 4; ++g) {
                    float s = 0.f;
#pragma unroll
                    for (int w8 = 0; w8 < 8; ++w8)
                        s += U.red[w8 * 2080 + (g * 8 + h8) * 65 + b];
                    z[g] = s + xzp[(size_t)(g * 512 + hid) * 64 + b];
                }
                float* cp = ws + WS_CT + (size_t)(dir * 512 + hid) * 64 + b;
                float cold = *cp;
                float ig = sigf(z[0]), fg = sigf(z[1]);
                float gg = tanhf(z[2]), og = sigf(z[3]);
                float cn = fg * cold + ig * gg;
                float hv = og * tanhf(cn);
                *cp = cn;
                ws[WS_HT + (size_t)(((p ^ 1) * 2 + dir) * 512 + hid) * 64 + b] = hv;
                int orow;
                if (dir == 0) orow = i;
                else { orow = lsh[b] - 1 - i; if (orow < 0) orow += T_DIM; }
                atomicAdd(&out[((size_t)orow * 64 + b) * 512 + hid], hv);
            }
        } else {
            // ===== role 2: transpose BN(x) rows for t=i+2 into yT ring (16 blocks) =====
            if (bid < 144 && i <= 1021) {
                const int idx = bid - 128;
                const int dir2 = idx & 1, bo = idx >> 1;   // 8 b-rows per block
                const int ttgt = i + 2;
#pragma unroll
                for (int it = 0; it < 2; ++it) {
                    int id2 = tid + it * 512;
                    int row = id2 >> 7;        // 0..7
                    int k4 = id2 & 127;
                    int b = bo * 8 + row;
                    int l = lsh[b];
                    int trow = dir2 ? (l - 1 - ttgt) : ttgt;
                    if (trow < 0) trow += T_DIM;
                    float m = (trow < l) ? 1.f : 0.f;
                    const float4 xv = *reinterpret_cast<const float4*>(
                        &x[((size_t)trow * 64 + b) * 512 + k4 * 4]);
                    float4 a4 = *reinterpret_cast<const float4*>(&a_sh[k4 * 4]);
                    float4 c4 = *reinterpret_cast<const float4*>(&c0_sh[k4 * 4]);
                    U.tile[(k4 * 4 + 0) * 9 + row] = (xv.x * a4.x + c4.x) * m;
                    U.tile[(k4 * 4 + 1) * 9 + row] = (xv.y * a4.y + c4.y) * m;
                    U.tile[(k4 * 4 + 2) * 9 + row] = (xv.z * a4.z + c4.z) * m;
                    U.tile[(k4 * 4 + 3) * 9 + row] = (xv.w * a4.w + c4.w) * m;
                }
                __syncthreads();
                const int q2 = ttgt & 1;
                float* yt = ws + WS_YT + (size_t)(q2 * 2 + dir2) * 512 * 64;
#pragma unroll
                for (int it = 0; it < 8; ++it) {
                    int gid = tid + it * 512;
                    int b = gid & 7;
                    int k = gid >> 3;
                    yt[(size_t)k * 64 + bo * 8 + b] = U.tile[k * 9 + b];
                }
                __syncthreads();
            }
            // ===== role 1: xz for t=i+1 =====
            if (i >= -1 && i <= 1022) {
                const int idx = bid - 128;
                const int dir = idx >> 6;
                const int cb = idx & 63;
                const int colbase = cb << 5;
                const int tt = i + 1;
                const int q = tt & 1;
                const float* __restrict__ Wx = dir ? Wx_b : Wx_f;
                const float* __restrict__ bv = dir ? b_b : b_f;
                const float* arow = ws + WS_YT + ((size_t)(q * 2 + dir) * 512 + kbase) * 64 + lane;
                const float* wp = Wx + (size_t)kbase * 2048 + colbase;
                float acc[32];
#pragma unroll
                for (int c = 0; c < 32; ++c) acc[c] = 0.f;
#pragma unroll 4
                for (int kk = 0; kk < 64; ++kk) {
                    float av = arow[kk * 64];
                    const float* wr = wp + (size_t)kk * 2048;
#pragma unroll
                    for (int c = 0; c < 32; ++c)
                        acc[c] = fmaf(wr[c], av, acc[c]);
                }
                __syncthreads();
#pragma unroll
                for (int c = 0; c < 32; ++c) U.red[w * 2080 + c * 65 + lane] = acc[c];
                __syncthreads();
                const int co2 = tid >> 4;          // 0..31 cols
                const int b4 = (tid & 15) << 2;    // b quad
                float bb = bv[colbase + co2];
                float r[4];
#pragma unroll
                for (int j = 0; j < 4; ++j) {
                    float s = 0.f;
#pragma unroll
                    for (int w8 = 0; w8 < 8; ++w8)
                        s += U.red[w8 * 2080 + co2 * 65 + b4 + j];
                    r[j] = s + bb;
                }
                *reinterpret_cast<float4*>(
                    &ws[WS_XZ + ((size_t)(q * 2 + dir) * 2048 + colbase + co2) * 64 + b4]) =
                    make_float4(r[0], r[1], r[2], r[3]);
            }
        }
        grid.sync();
    }
}

extern "C" void kernel_launch(void* const* d_in, const int* in_sizes, int n_in,
                              void* d_out, int out_size, void* d_ws, size_t ws_size,
                              hipStream_t stream) {
    const float* x        = (const float*)d_in[0];
    const int*   lengths  = (const int*)d_in[1];
    // d_in[2] = mask (recomputed from lengths on device)
    const float* scale    = (const float*)d_in[3];
    const float* bias     = (const float*)d_in[4];
    const float* Wx_f     = (const float*)d_in[5];
    const float* Wh_f     = (const float*)d_in[6];
    const float* b_f      = (const float*)d_in[7];
    const float* Wx_b     = (const float*)d_in[8];
    const float* Wh_b     = (const float*)d_in[9];
    const float* b_b      = (const float*)d_in[10];
    const int*   training = (const int*)d_in[11];
    float* ws  = (float*)d_ws;
    float* out = (float*)d_out;

    hipMemsetAsync(ws, 0, (size_t)WS_ZERO_END * sizeof(float), stream);
    hipMemsetAsync(out, 0, (size_t)out_size * sizeof(float), stream);

    void* args[] = {
        (void*)&x, (void*)&lengths, (void*)&scale, (void*)&bias,
        (void*)&Wx_f, (void*)&Wh_f, (void*)&b_f,
        (void*)&Wx_b, (void*)&Wh_b, (void*)&b_b,
        (void*)&training, (void*)&ws, (void*)&out
    };
    hipLaunchCooperativeKernel((const void*)brnn_persistent,
                               dim3(256), dim3(512), args, 0, stream);
}